// Round 19
// baseline (71.355 us; speedup 1.0000x reference)
//
#include <hip/hip_runtime.h>

#define DIMK 128
#define SLICE_TILES 4
#define NODES_PER_BLOCK 128

typedef __bf16 bf16x8 __attribute__((ext_vector_type(8)));
typedef float  f32x4  __attribute__((ext_vector_type(4)));

// ---- helpers ---------------------------------------------------------------
__device__ inline unsigned short f32_to_bf16_rne(float f) {
    unsigned u = __float_as_uint(f);
    u += 0x7FFFu + ((u >> 16) & 1u);      // round-to-nearest-even
    return (unsigned short)(u >> 16);
}

// Fragment-pack layout for a 16-row tile (= 2048 ushorts = 4KB):
//   ushort offset = tile*2048 + kk*512 + (kb*16 + col)*8 + j
// per-lane (lane = kb*16+col) a fragment load is base + kk*512 + lane*8.

// ---- kernel 1: FUSED pack of pred (scale 1) and target (scale -2) ----------
// Also counts segment sizes (one atomic per target row, 32 bins).
__global__ void pack_all(const float* __restrict__ pred,
                         const float* __restrict__ tgt,
                         const int* __restrict__ ids,
                         unsigned short* __restrict__ pb,
                         unsigned short* __restrict__ tb,
                         float* __restrict__ p2,
                         float* __restrict__ t2,
                         int* __restrict__ cnt,
                         int n_nodes, int n_rows_pad, int n_pos) {
    int wave = threadIdx.x >> 6, lane = threadIdx.x & 63;
    int row = blockIdx.x * 4 + wave;

    const float* src; unsigned short* dst; float* nrm; float scale; int r;
    if (row < n_rows_pad) {
        src = pred + (size_t)min(row, n_nodes - 1) * DIMK;
        dst = pb; nrm = p2; scale = 1.0f; r = row;
    } else {
        int trow = row - n_rows_pad;
        if (trow >= n_pos) return;
        src = tgt + (size_t)trow * DIMK;
        dst = tb; nrm = t2; scale = -2.0f; r = trow;
        if (lane == 0) atomicAdd(&cnt[ids[trow]], 1);   // histogram
    }
    int e = lane * 2;
    float2 v = *(const float2*)(src + e);
    unsigned pk = (unsigned)f32_to_bf16_rne(scale * v.x) |
                  ((unsigned)f32_to_bf16_rne(scale * v.y) << 16);
    int tile = r >> 4, col = r & 15;
    int kk = e >> 5, kb = (e >> 3) & 3, j = e & 7;
    size_t off = (size_t)tile * 2048 + kk * 512 + (kb * 16 + col) * 8 + j;
    *(unsigned*)(dst + off) = pk;           // j even -> dword aligned
    float s = v.x * v.x + v.y * v.y;        // norms from UNscaled values
#pragma unroll
    for (int o = 1; o < 64; o <<= 1) s += __shfl_xor(s, o, 64);
    if (lane == 0) nrm[r] = s;
}

// ---- kernel 2: per-position weight map (counts already in cnt) -------------
__global__ void wsa_map(const int* __restrict__ ids,
                        const int* __restrict__ nseg_p,
                        const int* __restrict__ cnt,
                        float* __restrict__ wsa, int n_pos) {
    int p = blockIdx.x * 256 + threadIdx.x;
    if (p >= n_pos) return;
    int nseg = nseg_p[0];
    wsa[p] = 1.0f / ((float)nseg * (float)max(cnt[ids[p]], 1));
}

// ---- kernel 3: fused cross-GEMM + sqrt + weighted reduce (r16, UNCHANGED) --
// 4-tile slice prestage, ONE sync, rotated tile order, split accumulation
// chains; t2/w staged in LDS; target packed with scale -2 so
// squared distance = d + t2 + p2.
__global__ __launch_bounds__(256, 6)
void l2dist_main(const unsigned short* __restrict__ pb,   // packed bf16 pred
                 const float* __restrict__ p2,
                 const unsigned short* __restrict__ tb,   // packed bf16(-2*t)
                 const float* __restrict__ t2g,
                 const float* __restrict__ wg,
                 float* __restrict__ out,
                 int n_nodes) {
    __shared__ __align__(16) unsigned short lbuf[SLICE_TILES][2048];  // 16 KB
    __shared__ __align__(16) float t2_lds[SLICE_TILES * 16];
    __shared__ __align__(16) float w_lds[SLICE_TILES * 16];

    const int tid  = threadIdx.x;
    const int lane = tid & 63;
    const int wave = tid >> 6;
    const int col  = lane & 15;
    const int kb   = lane >> 4;
    const int n0   = blockIdx.y * NODES_PER_BLOCK + wave * 32;

    // ---- stage the whole 4-tile slice first (longest latency) ----
    const int pbase = blockIdx.x * SLICE_TILES;
    const unsigned short* sgp = tb + (size_t)pbase * 2048 + wave * 512 + lane * 8;
    unsigned short* ldst = &lbuf[0][0] + wave * 512;
#pragma unroll
    for (int t = 0; t < SLICE_TILES; ++t) {
        __builtin_amdgcn_global_load_lds(
            (const __attribute__((address_space(1))) unsigned int*)(const void*)
                (sgp + (size_t)t * 2048),
            (__attribute__((address_space(3))) unsigned int*)(void*)
                (ldst + t * 2048),
            16, 0, 0);
    }

    // ---- t2 / w -> LDS (overlaps the stage) ----
    if (tid < SLICE_TILES * 16) {
        t2_lds[tid] = t2g[pbase * 16 + tid];
        w_lds[tid]  = wg[pbase * 16 + tid];
    }

    // ---- B fragments (2 node groups) + norms (overlaps the stage) ----
    bf16x8 bfrag[2][4];
    float p2g[2];
    const unsigned short* bp = pb + ((size_t)(n0 >> 4)) * 2048 + (size_t)lane * 8;
#pragma unroll
    for (int g = 0; g < 2; ++g) {
#pragma unroll
        for (int kk = 0; kk < 4; ++kk)
            bfrag[g][kk] = *(const bf16x8*)(bp + g * 2048 + kk * 512);
        p2g[g] = p2[n0 + g * 16 + col];
    }

    __syncthreads();    // drains stage + LDS writes; LDS read-only afterwards

    float acc0 = 0.f, acc1 = 0.f;
#pragma unroll
    for (int t = 0; t < SLICE_TILES; ++t) {
        const int te = (t + wave) & (SLICE_TILES - 1);   // de-phased order

        const unsigned short* rb = &lbuf[te][lane * 8];
        bf16x8 a0 = *(const bf16x8*)(rb);
        bf16x8 a1 = *(const bf16x8*)(rb + 512);
        bf16x8 a2 = *(const bf16x8*)(rb + 1024);
        bf16x8 a3 = *(const bf16x8*)(rb + 1536);

        f32x4 t2v = *(const f32x4*)&t2_lds[te * 16 + kb * 4];
        f32x4 wv  = *(const f32x4*)&w_lds[te * 16 + kb * 4];

        // 4 independent chains of depth 2 (dep distance 4 issues)
        f32x4 d0a = t2v + p2g[0];
        f32x4 d1a = t2v + p2g[1];
        f32x4 d0b = {0.f, 0.f, 0.f, 0.f};
        f32x4 d1b = {0.f, 0.f, 0.f, 0.f};
        d0a = __builtin_amdgcn_mfma_f32_16x16x32_bf16(a0, bfrag[0][0], d0a, 0, 0, 0);
        d1a = __builtin_amdgcn_mfma_f32_16x16x32_bf16(a0, bfrag[1][0], d1a, 0, 0, 0);
        d0b = __builtin_amdgcn_mfma_f32_16x16x32_bf16(a2, bfrag[0][2], d0b, 0, 0, 0);
        d1b = __builtin_amdgcn_mfma_f32_16x16x32_bf16(a2, bfrag[1][2], d1b, 0, 0, 0);
        d0a = __builtin_amdgcn_mfma_f32_16x16x32_bf16(a1, bfrag[0][1], d0a, 0, 0, 0);
        d1a = __builtin_amdgcn_mfma_f32_16x16x32_bf16(a1, bfrag[1][1], d1a, 0, 0, 0);
        d0b = __builtin_amdgcn_mfma_f32_16x16x32_bf16(a3, bfrag[0][3], d0b, 0, 0, 0);
        d1b = __builtin_amdgcn_mfma_f32_16x16x32_bf16(a3, bfrag[1][3], d1b, 0, 0, 0);

        f32x4 s0 = d0a + d0b;
        f32x4 s1 = d1a + d1b;
#pragma unroll
        for (int j = 0; j < 4; ++j) {
            acc0 = fmaf(wv[j], __builtin_amdgcn_sqrtf(fmaxf(s0[j], 0.f)), acc0);
            acc1 = fmaf(wv[j], __builtin_amdgcn_sqrtf(fmaxf(s1[j], 0.f)), acc1);
        }
    }

    // reduce over the 4 kb lane-groups -> per-node totals
    acc0 += __shfl_xor(acc0, 16, 64);
    acc0 += __shfl_xor(acc0, 32, 64);
    acc1 += __shfl_xor(acc1, 16, 64);
    acc1 += __shfl_xor(acc1, 32, 64);
    if (lane < 16) {
        int na = n0 + col;
        if (na      < n_nodes) atomicAdd(out + na,      acc0);
        if (na + 16 < n_nodes) atomicAdd(out + na + 16, acc1);
    }
}

// ---- launcher --------------------------------------------------------------
extern "C" void kernel_launch(void* const* d_in, const int* in_sizes, int n_in,
                              void* d_out, int out_size, void* d_ws, size_t ws_size,
                              hipStream_t stream) {
    const float* pred  = (const float*)d_in[0];
    const float* tgt   = (const float*)d_in[1];
    const int*   ids   = (const int*)d_in[2];
    const int*   nsegp = (const int*)d_in[3];
    float* out = (float*)d_out;

    int n_nodes = in_sizes[0] / DIMK;
    int n_pos   = in_sizes[2];

    int gy = (n_nodes + NODES_PER_BLOCK - 1) / NODES_PER_BLOCK;
    int n_rows_pad = gy * NODES_PER_BLOCK;

    char* ws = (char*)d_ws;
    size_t off_pb  = 0;                                        // packed bf16 pred
    size_t off_tb  = off_pb + (size_t)n_rows_pad * DIMK * 2;   // packed -2*target
    size_t off_p2  = off_tb + (size_t)n_pos * DIMK * 2;        // pred norms
    size_t off_t2  = off_p2 + (size_t)n_rows_pad * 4;          // target norms
    size_t off_w   = off_t2 + (size_t)n_pos * 4;               // weights
    size_t off_cnt = off_w  + (size_t)n_pos * 4;               // seg counts
    unsigned short* pb  = (unsigned short*)(ws + off_pb);
    unsigned short* tb  = (unsigned short*)(ws + off_tb);
    float*          p2  = (float*)(ws + off_p2);
    float*          t2  = (float*)(ws + off_t2);
    float*          wsa = (float*)(ws + off_w);
    int*            cnt = (int*)(ws + off_cnt);

    hipMemsetAsync(cnt, 0, 256 * sizeof(int), stream);         // zero histogram
    hipMemsetAsync(out, 0, (size_t)out_size * sizeof(float), stream);

    int prows = n_rows_pad + n_pos;          // fused pack grid
    pack_all<<<(prows + 3) / 4, 256, 0, stream>>>(pred, tgt, ids, pb, tb, p2, t2,
                                                  cnt, n_nodes, n_rows_pad, n_pos);
    wsa_map<<<(n_pos + 255) / 256, 256, 0, stream>>>(ids, nsegp, cnt, wsa, n_pos);

    int gx = (n_pos >> 4) / SLICE_TILES;     // 32 position slices (fast axis)
    dim3 grid(gx, gy);
    l2dist_main<<<grid, 256, 0, stream>>>(pb, p2, tb, t2, wsa, out, n_nodes);
}

// Round 20
// 54.731 us; speedup vs baseline: 1.3037x; 1.3037x over previous
//
#include <hip/hip_runtime.h>

#define DIMK 128
#define SLICE_TILES 4
#define NODES_PER_BLOCK 128

typedef __bf16 bf16x8 __attribute__((ext_vector_type(8)));
typedef float  f32x4  __attribute__((ext_vector_type(4)));

// ---- helpers ---------------------------------------------------------------
__device__ inline unsigned short f32_to_bf16_rne(float f) {
    unsigned u = __float_as_uint(f);
    u += 0x7FFFu + ((u >> 16) & 1u);      // round-to-nearest-even
    return (unsigned short)(u >> 16);
}

// Fragment-pack layout for a 16-row tile (= 2048 ushorts = 4KB):
//   ushort offset = tile*2048 + kk*512 + (kb*16 + col)*8 + j
// per-lane (lane = kb*16+col) a fragment load is base + kk*512 + lane*8.

// ---- kernel 1: FUSED pack of pred (scale 1) and target (scale -2) ----------
// Also zeroes out[] (coalesced strip per block) -> no memset graph node.
__global__ void pack_all(const float* __restrict__ pred,
                         const float* __restrict__ tgt,
                         unsigned short* __restrict__ pb,
                         unsigned short* __restrict__ tb,
                         float* __restrict__ p2,
                         float* __restrict__ t2,
                         float* __restrict__ out,
                         int n_nodes, int n_rows_pad, int n_pos) {
    // zero a 256-float strip of out (grid is ~13.5K blocks; 196 needed)
    int z = blockIdx.x * 256 + threadIdx.x;
    if (z < n_nodes) out[z] = 0.f;

    int wave = threadIdx.x >> 6, lane = threadIdx.x & 63;
    int row = blockIdx.x * 4 + wave;

    const float* src; unsigned short* dst; float* nrm; float scale; int r;
    if (row < n_rows_pad) {
        src = pred + (size_t)min(row, n_nodes - 1) * DIMK;
        dst = pb; nrm = p2; scale = 1.0f; r = row;
    } else {
        int trow = row - n_rows_pad;
        if (trow >= n_pos) return;
        src = tgt + (size_t)trow * DIMK;
        dst = tb; nrm = t2; scale = -2.0f; r = trow;
    }
    int e = lane * 2;
    float2 v = *(const float2*)(src + e);
    unsigned pk = (unsigned)f32_to_bf16_rne(scale * v.x) |
                  ((unsigned)f32_to_bf16_rne(scale * v.y) << 16);
    int tile = r >> 4, col = r & 15;
    int kk = e >> 5, kb = (e >> 3) & 3, j = e & 7;
    size_t off = (size_t)tile * 2048 + kk * 512 + (kb * 16 + col) * 8 + j;
    *(unsigned*)(dst + off) = pk;           // j even -> dword aligned
    float s = v.x * v.x + v.y * v.y;        // norms from UNscaled values
#pragma unroll
    for (int o = 1; o < 64; o <<= 1) s += __shfl_xor(s, o, 64);
    if (lane == 0) nrm[r] = s;
}

// ---- kernel 2: segment counts -> per-position weight array (SoA) -----------
__global__ void seg_weights(const int* __restrict__ ids,
                            const int* __restrict__ nseg_p,
                            float* __restrict__ wsa, int n_pos) {
    __shared__ int   cnt[256];
    __shared__ float w[256];
    int nseg = nseg_p[0];
    if (nseg > 256) nseg = 256;
    int t = threadIdx.x;
    if (t < nseg) cnt[t] = 0;
    __syncthreads();
    for (int p = t; p < n_pos; p += blockDim.x) atomicAdd(&cnt[ids[p]], 1);
    __syncthreads();
    if (t < nseg) w[t] = 1.0f / ((float)nseg * (float)max(cnt[t], 1));
    __syncthreads();
    for (int p = t; p < n_pos; p += blockDim.x) wsa[p] = w[ids[p]];
}

// ---- kernel 3: fused cross-GEMM + sqrt + weighted reduce (r16, UNCHANGED) --
// 4-tile slice prestage, ONE sync, rotated tile order, split accumulation
// chains; t2/w staged in LDS; target packed with scale -2 so
// squared distance = d + t2 + p2.
__global__ __launch_bounds__(256, 6)
void l2dist_main(const unsigned short* __restrict__ pb,   // packed bf16 pred
                 const float* __restrict__ p2,
                 const unsigned short* __restrict__ tb,   // packed bf16(-2*t)
                 const float* __restrict__ t2g,
                 const float* __restrict__ wg,
                 float* __restrict__ out,
                 int n_nodes) {
    __shared__ __align__(16) unsigned short lbuf[SLICE_TILES][2048];  // 16 KB
    __shared__ __align__(16) float t2_lds[SLICE_TILES * 16];
    __shared__ __align__(16) float w_lds[SLICE_TILES * 16];

    const int tid  = threadIdx.x;
    const int lane = tid & 63;
    const int wave = tid >> 6;
    const int col  = lane & 15;
    const int kb   = lane >> 4;
    const int n0   = blockIdx.y * NODES_PER_BLOCK + wave * 32;

    // ---- stage the whole 4-tile slice first (longest latency) ----
    const int pbase = blockIdx.x * SLICE_TILES;
    const unsigned short* sgp = tb + (size_t)pbase * 2048 + wave * 512 + lane * 8;
    unsigned short* ldst = &lbuf[0][0] + wave * 512;
#pragma unroll
    for (int t = 0; t < SLICE_TILES; ++t) {
        __builtin_amdgcn_global_load_lds(
            (const __attribute__((address_space(1))) unsigned int*)(const void*)
                (sgp + (size_t)t * 2048),
            (__attribute__((address_space(3))) unsigned int*)(void*)
                (ldst + t * 2048),
            16, 0, 0);
    }

    // ---- t2 / w -> LDS (overlaps the stage) ----
    if (tid < SLICE_TILES * 16) {
        t2_lds[tid] = t2g[pbase * 16 + tid];
        w_lds[tid]  = wg[pbase * 16 + tid];
    }

    // ---- B fragments (2 node groups) + norms (overlaps the stage) ----
    bf16x8 bfrag[2][4];
    float p2g[2];
    const unsigned short* bp = pb + ((size_t)(n0 >> 4)) * 2048 + (size_t)lane * 8;
#pragma unroll
    for (int g = 0; g < 2; ++g) {
#pragma unroll
        for (int kk = 0; kk < 4; ++kk)
            bfrag[g][kk] = *(const bf16x8*)(bp + g * 2048 + kk * 512);
        p2g[g] = p2[n0 + g * 16 + col];
    }

    __syncthreads();    // drains stage + LDS writes; LDS read-only afterwards

    float acc0 = 0.f, acc1 = 0.f;
#pragma unroll
    for (int t = 0; t < SLICE_TILES; ++t) {
        const int te = (t + wave) & (SLICE_TILES - 1);   // de-phased order

        const unsigned short* rb = &lbuf[te][lane * 8];
        bf16x8 a0 = *(const bf16x8*)(rb);
        bf16x8 a1 = *(const bf16x8*)(rb + 512);
        bf16x8 a2 = *(const bf16x8*)(rb + 1024);
        bf16x8 a3 = *(const bf16x8*)(rb + 1536);

        f32x4 t2v = *(const f32x4*)&t2_lds[te * 16 + kb * 4];
        f32x4 wv  = *(const f32x4*)&w_lds[te * 16 + kb * 4];

        // 4 independent chains of depth 2 (dep distance 4 issues)
        f32x4 d0a = t2v + p2g[0];
        f32x4 d1a = t2v + p2g[1];
        f32x4 d0b = {0.f, 0.f, 0.f, 0.f};
        f32x4 d1b = {0.f, 0.f, 0.f, 0.f};
        d0a = __builtin_amdgcn_mfma_f32_16x16x32_bf16(a0, bfrag[0][0], d0a, 0, 0, 0);
        d1a = __builtin_amdgcn_mfma_f32_16x16x32_bf16(a0, bfrag[1][0], d1a, 0, 0, 0);
        d0b = __builtin_amdgcn_mfma_f32_16x16x32_bf16(a2, bfrag[0][2], d0b, 0, 0, 0);
        d1b = __builtin_amdgcn_mfma_f32_16x16x32_bf16(a2, bfrag[1][2], d1b, 0, 0, 0);
        d0a = __builtin_amdgcn_mfma_f32_16x16x32_bf16(a1, bfrag[0][1], d0a, 0, 0, 0);
        d1a = __builtin_amdgcn_mfma_f32_16x16x32_bf16(a1, bfrag[1][1], d1a, 0, 0, 0);
        d0b = __builtin_amdgcn_mfma_f32_16x16x32_bf16(a3, bfrag[0][3], d0b, 0, 0, 0);
        d1b = __builtin_amdgcn_mfma_f32_16x16x32_bf16(a3, bfrag[1][3], d1b, 0, 0, 0);

        f32x4 s0 = d0a + d0b;
        f32x4 s1 = d1a + d1b;
#pragma unroll
        for (int j = 0; j < 4; ++j) {
            acc0 = fmaf(wv[j], __builtin_amdgcn_sqrtf(fmaxf(s0[j], 0.f)), acc0);
            acc1 = fmaf(wv[j], __builtin_amdgcn_sqrtf(fmaxf(s1[j], 0.f)), acc1);
        }
    }

    // reduce over the 4 kb lane-groups -> per-node totals
    acc0 += __shfl_xor(acc0, 16, 64);
    acc0 += __shfl_xor(acc0, 32, 64);
    acc1 += __shfl_xor(acc1, 16, 64);
    acc1 += __shfl_xor(acc1, 32, 64);
    if (lane < 16) {
        int na = n0 + col;
        if (na      < n_nodes) atomicAdd(out + na,      acc0);
        if (na + 16 < n_nodes) atomicAdd(out + na + 16, acc1);
    }
}

// ---- launcher: 3 graph nodes total ------------------------------------------
extern "C" void kernel_launch(void* const* d_in, const int* in_sizes, int n_in,
                              void* d_out, int out_size, void* d_ws, size_t ws_size,
                              hipStream_t stream) {
    const float* pred  = (const float*)d_in[0];
    const float* tgt   = (const float*)d_in[1];
    const int*   ids   = (const int*)d_in[2];
    const int*   nsegp = (const int*)d_in[3];
    float* out = (float*)d_out;

    int n_nodes = in_sizes[0] / DIMK;
    int n_pos   = in_sizes[2];

    int gy = (n_nodes + NODES_PER_BLOCK - 1) / NODES_PER_BLOCK;
    int n_rows_pad = gy * NODES_PER_BLOCK;

    char* ws = (char*)d_ws;
    size_t off_pb = 0;                                        // packed bf16 pred
    size_t off_tb = off_pb + (size_t)n_rows_pad * DIMK * 2;   // packed -2*target
    size_t off_p2 = off_tb + (size_t)n_pos * DIMK * 2;        // pred norms
    size_t off_t2 = off_p2 + (size_t)n_rows_pad * 4;          // target norms
    size_t off_w  = off_t2 + (size_t)n_pos * 4;               // weights
    unsigned short* pb  = (unsigned short*)(ws + off_pb);
    unsigned short* tb  = (unsigned short*)(ws + off_tb);
    float*          p2  = (float*)(ws + off_p2);
    float*          t2  = (float*)(ws + off_t2);
    float*          wsa = (float*)(ws + off_w);

    int prows = n_rows_pad + n_pos;          // fused pack grid (zeroes out too)
    pack_all<<<(prows + 3) / 4, 256, 0, stream>>>(pred, tgt, pb, tb, p2, t2,
                                                  out, n_nodes, n_rows_pad, n_pos);
    seg_weights<<<1, 1024, 0, stream>>>(ids, nsegp, wsa, n_pos);

    int gx = (n_pos >> 4) / SLICE_TILES;     // 32 position slices (fast axis)
    dim3 grid(gx, gy);
    l2dist_main<<<grid, 256, 0, stream>>>(pb, p2, tb, t2, wsa, out, n_nodes);
}

// Round 21
// 52.107 us; speedup vs baseline: 1.3694x; 1.0504x over previous
//
#include <hip/hip_runtime.h>

#define DIMK 128
#define SLICE_TILES 4
#define NODES_PER_BLOCK 128

typedef __bf16 bf16x8 __attribute__((ext_vector_type(8)));
typedef float  f32x4  __attribute__((ext_vector_type(4)));

// ---- helpers ---------------------------------------------------------------
__device__ inline unsigned short f32_to_bf16_rne(float f) {
    unsigned u = __float_as_uint(f);
    u += 0x7FFFu + ((u >> 16) & 1u);      // round-to-nearest-even
    return (unsigned short)(u >> 16);
}

// Fragment-pack layout for a 16-row tile (= 2048 ushorts = 4KB):
//   ushort offset = tile*2048 + kk*512 + (kb*16 + col)*8 + j
// per-lane (lane = kb*16+col) a fragment load is base + kk*512 + lane*8.
// Dword view: tile*1024 + t*4 .. t*4+3 for t = kk*64 + kb*16 + col.

// ---- kernel 1: tile-coalesced pack of pred (scale 1) / target (scale -2) ---
// One block per 16-row tile; thread t writes dwords 4t..4t+3 of the tile as
// ONE aligned 16B store (fully coalesced). Also zeroes out[] strips.
__global__ void pack_tiles(const float* __restrict__ pred,
                           const float* __restrict__ tgt,
                           unsigned short* __restrict__ pb,
                           unsigned short* __restrict__ tb,
                           float* __restrict__ p2,
                           float* __restrict__ t2,
                           float* __restrict__ out,
                           int n_nodes, int n_tiles_pred, int n_pos) {
    __shared__ float nrm_lds[16];
    const int tid = threadIdx.x;
    const int b   = blockIdx.x;

    // zero a 256-float strip of out (first 196 blocks cover n_nodes)
    int z = b * 256 + tid;
    if (z < n_nodes) out[z] = 0.f;

    const int col = tid & 15;            // row within tile
    const int kb  = (tid & 63) >> 4;
    const int kk  = tid >> 6;            // == wave index

    const float* src; unsigned short* dst; float* nrm; float scale; int tile;
    if (b < n_tiles_pred) {
        tile = b;
        int row = tile * 16 + col;
        src = pred + (size_t)min(row, n_nodes - 1) * DIMK;
        dst = pb; nrm = p2; scale = 1.0f;
    } else {
        tile = b - n_tiles_pred;         // n_pos % 16 == 0 (2048)
        int row = tile * 16 + col;
        src = tgt + (size_t)row * DIMK;
        dst = tb; nrm = t2; scale = -2.0f;
    }

    if (tid < 16) nrm_lds[tid] = 0.f;
    __syncthreads();

    const int ebase = kk * 32 + kb * 8;  // this thread's 8-element k-window
    f32x4 v0 = *(const f32x4*)(src + ebase);
    f32x4 v1 = *(const f32x4*)(src + ebase + 4);

    unsigned pk0 = (unsigned)f32_to_bf16_rne(scale * v0[0]) |
                   ((unsigned)f32_to_bf16_rne(scale * v0[1]) << 16);
    unsigned pk1 = (unsigned)f32_to_bf16_rne(scale * v0[2]) |
                   ((unsigned)f32_to_bf16_rne(scale * v0[3]) << 16);
    unsigned pk2 = (unsigned)f32_to_bf16_rne(scale * v1[0]) |
                   ((unsigned)f32_to_bf16_rne(scale * v1[1]) << 16);
    unsigned pk3 = (unsigned)f32_to_bf16_rne(scale * v1[2]) |
                   ((unsigned)f32_to_bf16_rne(scale * v1[3]) << 16);
    uint4 pkv = {pk0, pk1, pk2, pk3};
    *(uint4*)(dst + (size_t)tile * 2048 + tid * 8) = pkv;   // coalesced b128

    // row norms (unscaled): reduce the 4 kb-partials per col within the wave
    float s = v0[0]*v0[0] + v0[1]*v0[1] + v0[2]*v0[2] + v0[3]*v0[3]
            + v1[0]*v1[0] + v1[1]*v1[1] + v1[2]*v1[2] + v1[3]*v1[3];
    s += __shfl_xor(s, 16, 64);
    s += __shfl_xor(s, 32, 64);          // lanes 0-15 hold per-col sums (this kk)
    if ((tid & 63) < 16) atomicAdd(&nrm_lds[col], s);
    __syncthreads();
    if (tid < 16) nrm[tile * 16 + tid] = nrm_lds[tid];
}

// ---- kernel 2: segment counts -> per-position weight array (SoA) -----------
__global__ void seg_weights(const int* __restrict__ ids,
                            const int* __restrict__ nseg_p,
                            float* __restrict__ wsa, int n_pos) {
    __shared__ int   cnt[256];
    __shared__ float w[256];
    int nseg = nseg_p[0];
    if (nseg > 256) nseg = 256;
    int t = threadIdx.x;
    if (t < nseg) cnt[t] = 0;
    __syncthreads();
    for (int p = t; p < n_pos; p += blockDim.x) atomicAdd(&cnt[ids[p]], 1);
    __syncthreads();
    if (t < nseg) w[t] = 1.0f / ((float)nseg * (float)max(cnt[t], 1));
    __syncthreads();
    for (int p = t; p < n_pos; p += blockDim.x) wsa[p] = w[ids[p]];
}

// ---- kernel 3: fused cross-GEMM + sqrt + weighted reduce (r16, UNCHANGED) --
// 4-tile slice prestage, ONE sync, rotated tile order, split accumulation
// chains; t2/w staged in LDS; target packed with scale -2 so
// squared distance = d + t2 + p2.
__global__ __launch_bounds__(256, 6)
void l2dist_main(const unsigned short* __restrict__ pb,   // packed bf16 pred
                 const float* __restrict__ p2,
                 const unsigned short* __restrict__ tb,   // packed bf16(-2*t)
                 const float* __restrict__ t2g,
                 const float* __restrict__ wg,
                 float* __restrict__ out,
                 int n_nodes) {
    __shared__ __align__(16) unsigned short lbuf[SLICE_TILES][2048];  // 16 KB
    __shared__ __align__(16) float t2_lds[SLICE_TILES * 16];
    __shared__ __align__(16) float w_lds[SLICE_TILES * 16];

    const int tid  = threadIdx.x;
    const int lane = tid & 63;
    const int wave = tid >> 6;
    const int col  = lane & 15;
    const int kb   = lane >> 4;
    const int n0   = blockIdx.y * NODES_PER_BLOCK + wave * 32;

    // ---- stage the whole 4-tile slice first (longest latency) ----
    const int pbase = blockIdx.x * SLICE_TILES;
    const unsigned short* sgp = tb + (size_t)pbase * 2048 + wave * 512 + lane * 8;
    unsigned short* ldst = &lbuf[0][0] + wave * 512;
#pragma unroll
    for (int t = 0; t < SLICE_TILES; ++t) {
        __builtin_amdgcn_global_load_lds(
            (const __attribute__((address_space(1))) unsigned int*)(const void*)
                (sgp + (size_t)t * 2048),
            (__attribute__((address_space(3))) unsigned int*)(void*)
                (ldst + t * 2048),
            16, 0, 0);
    }

    // ---- t2 / w -> LDS (overlaps the stage) ----
    if (tid < SLICE_TILES * 16) {
        t2_lds[tid] = t2g[pbase * 16 + tid];
        w_lds[tid]  = wg[pbase * 16 + tid];
    }

    // ---- B fragments (2 node groups) + norms (overlaps the stage) ----
    bf16x8 bfrag[2][4];
    float p2g[2];
    const unsigned short* bp = pb + ((size_t)(n0 >> 4)) * 2048 + (size_t)lane * 8;
#pragma unroll
    for (int g = 0; g < 2; ++g) {
#pragma unroll
        for (int kk = 0; kk < 4; ++kk)
            bfrag[g][kk] = *(const bf16x8*)(bp + g * 2048 + kk * 512);
        p2g[g] = p2[n0 + g * 16 + col];
    }

    __syncthreads();    // drains stage + LDS writes; LDS read-only afterwards

    float acc0 = 0.f, acc1 = 0.f;
#pragma unroll
    for (int t = 0; t < SLICE_TILES; ++t) {
        const int te = (t + wave) & (SLICE_TILES - 1);   // de-phased order

        const unsigned short* rb = &lbuf[te][lane * 8];
        bf16x8 a0 = *(const bf16x8*)(rb);
        bf16x8 a1 = *(const bf16x8*)(rb + 512);
        bf16x8 a2 = *(const bf16x8*)(rb + 1024);
        bf16x8 a3 = *(const bf16x8*)(rb + 1536);

        f32x4 t2v = *(const f32x4*)&t2_lds[te * 16 + kb * 4];
        f32x4 wv  = *(const f32x4*)&w_lds[te * 16 + kb * 4];

        // 4 independent chains of depth 2 (dep distance 4 issues)
        f32x4 d0a = t2v + p2g[0];
        f32x4 d1a = t2v + p2g[1];
        f32x4 d0b = {0.f, 0.f, 0.f, 0.f};
        f32x4 d1b = {0.f, 0.f, 0.f, 0.f};
        d0a = __builtin_amdgcn_mfma_f32_16x16x32_bf16(a0, bfrag[0][0], d0a, 0, 0, 0);
        d1a = __builtin_amdgcn_mfma_f32_16x16x32_bf16(a0, bfrag[1][0], d1a, 0, 0, 0);
        d0b = __builtin_amdgcn_mfma_f32_16x16x32_bf16(a2, bfrag[0][2], d0b, 0, 0, 0);
        d1b = __builtin_amdgcn_mfma_f32_16x16x32_bf16(a2, bfrag[1][2], d1b, 0, 0, 0);
        d0a = __builtin_amdgcn_mfma_f32_16x16x32_bf16(a1, bfrag[0][1], d0a, 0, 0, 0);
        d1a = __builtin_amdgcn_mfma_f32_16x16x32_bf16(a1, bfrag[1][1], d1a, 0, 0, 0);
        d0b = __builtin_amdgcn_mfma_f32_16x16x32_bf16(a3, bfrag[0][3], d0b, 0, 0, 0);
        d1b = __builtin_amdgcn_mfma_f32_16x16x32_bf16(a3, bfrag[1][3], d1b, 0, 0, 0);

        f32x4 s0 = d0a + d0b;
        f32x4 s1 = d1a + d1b;
#pragma unroll
        for (int j = 0; j < 4; ++j) {
            acc0 = fmaf(wv[j], __builtin_amdgcn_sqrtf(fmaxf(s0[j], 0.f)), acc0);
            acc1 = fmaf(wv[j], __builtin_amdgcn_sqrtf(fmaxf(s1[j], 0.f)), acc1);
        }
    }

    // reduce over the 4 kb lane-groups -> per-node totals
    acc0 += __shfl_xor(acc0, 16, 64);
    acc0 += __shfl_xor(acc0, 32, 64);
    acc1 += __shfl_xor(acc1, 16, 64);
    acc1 += __shfl_xor(acc1, 32, 64);
    if (lane < 16) {
        int na = n0 + col;
        if (na      < n_nodes) atomicAdd(out + na,      acc0);
        if (na + 16 < n_nodes) atomicAdd(out + na + 16, acc1);
    }
}

// ---- launcher: 3 graph nodes total ------------------------------------------
extern "C" void kernel_launch(void* const* d_in, const int* in_sizes, int n_in,
                              void* d_out, int out_size, void* d_ws, size_t ws_size,
                              hipStream_t stream) {
    const float* pred  = (const float*)d_in[0];
    const float* tgt   = (const float*)d_in[1];
    const int*   ids   = (const int*)d_in[2];
    const int*   nsegp = (const int*)d_in[3];
    float* out = (float*)d_out;

    int n_nodes = in_sizes[0] / DIMK;
    int n_pos   = in_sizes[2];

    int gy = (n_nodes + NODES_PER_BLOCK - 1) / NODES_PER_BLOCK;
    int n_rows_pad = gy * NODES_PER_BLOCK;
    int n_tiles_pred = n_rows_pad >> 4;

    char* ws = (char*)d_ws;
    size_t off_pb = 0;                                        // packed bf16 pred
    size_t off_tb = off_pb + (size_t)n_rows_pad * DIMK * 2;   // packed -2*target
    size_t off_p2 = off_tb + (size_t)n_pos * DIMK * 2;        // pred norms
    size_t off_t2 = off_p2 + (size_t)n_rows_pad * 4;          // target norms
    size_t off_w  = off_t2 + (size_t)n_pos * 4;               // weights
    unsigned short* pb  = (unsigned short*)(ws + off_pb);
    unsigned short* tb  = (unsigned short*)(ws + off_tb);
    float*          p2  = (float*)(ws + off_p2);
    float*          t2  = (float*)(ws + off_t2);
    float*          wsa = (float*)(ws + off_w);

    int nblocks = n_tiles_pred + (n_pos >> 4);   // one block per 16-row tile
    pack_tiles<<<nblocks, 256, 0, stream>>>(pred, tgt, pb, tb, p2, t2, out,
                                            n_nodes, n_tiles_pred, n_pos);
    seg_weights<<<1, 1024, 0, stream>>>(ids, nsegp, wsa, n_pos);

    int gx = (n_pos >> 4) / SLICE_TILES;     // 32 position slices (fast axis)
    dim3 grid(gx, gy);
    l2dist_main<<<grid, 256, 0, stream>>>(pb, p2, tb, t2, wsa, out, n_nodes);
}